// Round 12
// baseline (113.877 us; speedup 1.0000x reference)
//
#include <hip/hip_runtime.h>
#include <math.h>

// CTC loss forward: T=1024, N=128, C=256, S=64, L=2S+1=129, blank=0.
constexpr int kT = 1024;
constexpr int kN = 128;
constexpr int kC = 256;
constexpr float NEGV = -1e30f;
constexpr int kRow = 260;            // floats per t4-group: 65 states x 4 t's
constexpr int kCH = 32;              // t-steps per chunk per direction
constexpr int kNCH = 512 / kCH;      // 16 chunks per direction
constexpr int kChF = 8 * kRow;       // 2080 floats per chunk (8 t4-groups)
constexpr float LOG2E = 1.4426950408889634f;
constexpr float LN2 = 0.6931471805599453f;

#if __has_builtin(__builtin_amdgcn_exp2f)
#define EXP2(x) __builtin_amdgcn_exp2f(x)
#else
#define EXP2(x) exp2f(x)
#endif
#if __has_builtin(__builtin_amdgcn_logf)
#define LOG2(x) __builtin_amdgcn_logf(x)
#else
#define LOG2(x) log2f(x)
#endif

struct TrueT { static constexpr bool value = true; };
struct FalseT { static constexpr bool value = false; };

__device__ __forceinline__ float lse2_2(float a, float b) {  // log2(2^a + 2^b)
    const float m = fmaxf(a, b);
    const float d = fminf(a, b) - m;
    return m + LOG2(1.0f + EXP2(d));
}

// One DP step, log2 domain (validated r7/r11). Works for BOTH directions:
// fwd: A,B = alpha[2l], alpha[2l+1]; C = alpha[128] (lane 0); shuffle = B[l-1],
//      wrap lane0 <- B[63].
// bwd (reversed lane map): A,B = beta[128-2l], beta[127-2l]; C = beta[0]
//      (lane 0); identical shuffle/boundary structure (exact mirror).
template <bool FRZ>
__device__ __forceinline__ void dp_step(float& A, float& B, float& C,
                                        float lpb, float lpy, bool skip,
                                        int lgrp, int l, bool commit) {
    const int bi = __float_as_int(B);
    const int b15 = __builtin_amdgcn_readlane(bi, 15);
    const int b31 = __builtin_amdgcn_readlane(bi, 31);
    const int b47 = __builtin_amdgcn_readlane(bi, 47);
    const int b63 = __builtin_amdgcn_readlane(bi, 63);
    const int bndi = (lgrp == 0) ? b63 : (lgrp == 1) ? b15 : (lgrp == 2) ? b31 : b47;
    const float am1 = __int_as_float(__builtin_amdgcn_update_dpp(
        bndi, bi, 0x111 /*row_shr:1*/, 0xF, 0xF, false));
    const float am1s = skip ? am1 : NEGV;
    // nB = lpy + lse3(B, A, am1s): med3 2-exp form
    const float x = fmaxf(B, A), yv = fminf(B, A);
    const float mB = fmaxf(x, am1s);
    const float dB1 = fmaxf(yv, fminf(x, am1s)) - mB;  // med - max
    const float dB2 = fminf(yv, am1s) - mB;            // min - max
    const float nB = (lpy + mB) + LOG2(1.0f + (EXP2(dB1) + EXP2(dB2)));
    // even-state / extra-state share one lse2 (lane 0's slot computes C)
    const float u = (l == 0) ? C : A;
    const float mA = fmaxf(u, am1);
    const float lseA = mA + LOG2(1.0f + EXP2(fminf(u, am1) - mA));
    const float nA = lpb + ((l == 0) ? A : lseA);
    const float nC = lpb + lseA;  // meaningful at lane 0 only
    if (FRZ) {
        A = commit ? nA : A;
        B = commit ? nB : B;
        C = commit ? nC : C;
    } else {
        A = nA; B = nB; C = nC;
    }
}

// Fused kernel: softmax+gather AND split fwd/bwd DP. One block per batch item,
// 8 waves: w0 = alpha (t=1..511), w1 = beta (t=1023..512, reversed lane map),
// w2-4 compute+stage the fwd lp stream from raw logits, w5-7 the bwd stream.
// Merge: nll = -lse_s(alpha_511[s] + gamma_511[s]).
__global__ __launch_bounds__(512) void k_ctc_fused(const float* __restrict__ logits,
                                                   const int* __restrict__ y,
                                                   const int* __restrict__ xlens,
                                                   const int* __restrict__ ylens,
                                                   float* __restrict__ nll_out) {
    __shared__ alignas(16) float sbf[2][kChF];   // fwd lp chunks [t4][s][j]
    __shared__ alignas(16) float sbb[2][kChF];   // bwd lp chunks (ascending t)
    __shared__ alignas(16) float scr[6][kC];     // per-stager-wave row scratch
    __shared__ float st_f[130];
    __shared__ float st_b[130];
    const int n = blockIdx.x;
    const int wid = threadIdx.x >> 6;
    const int l = threadIdx.x & 63;
    const int lgrp = l >> 4;

    const int yl = ylens[n];
    const int xl = xlens[n];
    const int cls = y[(n << 6) + l];  // label for slot l (in [1, C))

    // ---------------- stager: softmax+gather one 32-t chunk into LDS --------
    // 3 waves per direction; wave widx handles rows r = widx, widx+3, ...
    auto stage_sm = [&](int c, bool isF, float* dst) {
        const int widx = isF ? (wid - 2) : (wid - 5);
        const int scrw = wid - 2;  // 0..5
        float4 v0, v1, v2, v3, v4, v5, v6, v7, v8, v9, v10;
#define ROWT(K) (isF ? (c * kCH + widx + 3 * (K)) : (992 - kCH * c + widx + 3 * (K)))
#define LOADR(K, V)                                                           \
    do {                                                                      \
        if (widx + 3 * (K) < kCH) {                                           \
            const int tg_ = ROWT(K);                                          \
            V = *reinterpret_cast<const float4*>(                             \
                logits + ((size_t)tg_ * kN + n) * kC + 4 * l);                \
        }                                                                     \
    } while (0)
        LOADR(0, v0); LOADR(1, v1); LOADR(2, v2); LOADR(3, v3);
        LOADR(4, v4); LOADR(5, v5); LOADR(6, v6); LOADR(7, v7);
        LOADR(8, v8); LOADR(9, v9); LOADR(10, v10);
#define PROCR(K, V)                                                           \
    do {                                                                      \
        const int r_ = widx + 3 * (K);                                        \
        if (r_ < kCH) {                                                       \
            float m_ = fmaxf(fmaxf(V.x, V.y), fmaxf(V.z, V.w));               \
            _Pragma("unroll") for (int o_ = 32; o_ > 0; o_ >>= 1)             \
                m_ = fmaxf(m_, __shfl_xor(m_, o_));                           \
            float s_ = __expf(V.x - m_) + __expf(V.y - m_) +                  \
                       __expf(V.z - m_) + __expf(V.w - m_);                   \
            _Pragma("unroll") for (int o_ = 32; o_ > 0; o_ >>= 1)             \
                s_ += __shfl_xor(s_, o_);                                     \
            const float l2s_ = LOG2(s_);                                      \
            reinterpret_cast<float4*>(&scr[scrw][0])[l] = V;                  \
            const float g_ = scr[scrw][cls];                                  \
            const int t4_ = r_ >> 2, j_ = r_ & 3;                             \
            dst[t4_ * kRow + (1 + l) * 4 + j_] = (g_ - m_) * LOG2E - l2s_;    \
            if (l == 0) dst[t4_ * kRow + j_] = (V.x - m_) * LOG2E - l2s_;     \
        }                                                                     \
    } while (0)
        PROCR(0, v0); PROCR(1, v1); PROCR(2, v2); PROCR(3, v3);
        PROCR(4, v4); PROCR(5, v5); PROCR(6, v6); PROCR(7, v7);
        PROCR(8, v8); PROCR(9, v9); PROCR(10, v10);
#undef PROCR
#undef LOADR
#undef ROWT
    };

    if (wid >= 2) stage_sm(0, wid < 5, (wid < 5) ? sbf[0] : sbb[0]);
    __syncthreads();

    if (wid == 0) {
        // ---------------- FORWARD: alpha, t = 1..511 ----------------
        const int yprev = __shfl_up(cls, 1);
        const bool skip = (l >= 1) && (cls != yprev);
        float aA = (l == 0) ? sbf[0][0] : NEGV;  // lp[t=0][s=0]
        float aB = (l == 0) ? sbf[0][4] : NEGV;  // lp[t=0][s=1]
        float aC = NEGV;

        for (int c = 0; c < kNCH; ++c) {
            const float* B = sbf[c & 1];
            const int tb0 = c * kCH;
            auto body = [&](auto frzc) {
                constexpr bool FRZV = decltype(frzc)::value;
                float pb[2][4][4], py[2][4][4];
#define LOADF(H, D)                                                          \
    do {                                                                     \
        _Pragma("unroll") for (int q_ = 0; q_ < 4; ++q_) {                   \
            const int rb_ = (4 * (H) + q_) * kRow;                           \
            const float4 t0_ = *(const float4*)&B[rb_];                      \
            const float4 t1_ = *(const float4*)&B[rb_ + 4 + 4 * l];          \
            pb[D][q_][0] = t0_.x; pb[D][q_][1] = t0_.y;                      \
            pb[D][q_][2] = t0_.z; pb[D][q_][3] = t0_.w;                      \
            py[D][q_][0] = t1_.x; py[D][q_][1] = t1_.y;                      \
            py[D][q_][2] = t1_.z; py[D][q_][3] = t1_.w;                      \
        }                                                                    \
    } while (0)
                LOADF(0, 0);
#pragma unroll
                for (int h = 0; h < 2; ++h) {
                    const int cur = h & 1;
                    if (h < 1) LOADF(1, 1);
#pragma unroll
                    for (int q = 0; q < 4; ++q) {
#pragma unroll
                        for (int j = 0; j < 4; ++j) {
                            const int t = tb0 + 16 * h + 4 * q + j;
                            dp_step<FRZV>(aA, aB, aC, pb[cur][q][j], py[cur][q][j],
                                          skip, lgrp, l, (t > 0) & (t < xl));
                        }
                    }
                }
#undef LOADF
            };
            if (c == 0 || xl < 512) body(TrueT{});
            else body(FalseT{});
            __syncthreads();
        }
        st_f[2 * l] = aA;
        st_f[2 * l + 1] = aB;
        if (l == 0) st_f[128] = aC;
        __syncthreads();

        // ---------------- MERGE ----------------
        const float v0 = st_f[l] + st_b[l];
        const float v1 = st_f[64 + l] + st_b[64 + l];
        const float v2 = (l == 0) ? (st_f[128] + st_b[128]) : NEGV;
        float mm = fmaxf(fmaxf(v0, v1), v2);
#pragma unroll
        for (int o = 32; o > 0; o >>= 1) mm = fmaxf(mm, __shfl_xor(mm, o));
        float sm = EXP2(v0 - mm) + EXP2(v1 - mm) + EXP2(v2 - mm);
#pragma unroll
        for (int o = 32; o > 0; o >>= 1) sm += __shfl_xor(sm, o);
        if (l == 0) {
            float nll;
            if (xl <= 512) {  // beta segment empty: read frozen alpha directly
                nll = -lse2_2(st_f[2 * yl], st_f[2 * yl - 1]) * LN2;
            } else {
                nll = -(mm + LOG2(sm)) * LN2;
            }
            if (!(isfinite(nll) && nll < 1e29f)) nll = 0.0f;  // zero_infinity
            nll_out[n] = nll / (float)yl;
        }
    } else if (wid == 1) {
        // ---------------- BACKWARD: beta, t = 1023..512 (reversed lanes) ----
        // lane l owns states (128-2l, 127-2l); state 0 in lane 0's extra slot.
        const int ycb = y[(n << 6) + 63 - l];     // label of state 127-2l
        const int yup = __shfl_up(ycb, 1);        // y[64-l]
        const bool skipb = (l >= 1) && (ycb != yup);
        const int ls = 64 - yl;                   // seed lane (yl=64 -> 0)
        float bA = NEGV, bB = NEGV, b0 = NEGV;

        for (int c = 0; c < kNCH; ++c) {
            const float* B = sbb[c & 1];
            const int ttop = 1023 - kCH * c;      // t of first (descending) slot
            auto body = [&](auto frzc) {
                constexpr bool FRZV = decltype(frzc)::value;
                float pb[2][4][4], py[2][4][4];
#define LOADB(H, D)                                                          \
    do {                                                                     \
        _Pragma("unroll") for (int q_ = 0; q_ < 4; ++q_) {                   \
            const int rb_ = (7 - 4 * (H) - q_) * kRow;                       \
            const float4 t0_ = *(const float4*)&B[rb_];                      \
            const float4 t1_ = *(const float4*)&B[rb_ + 256 - 4 * l];        \
            pb[D][q_][0] = t0_.x; pb[D][q_][1] = t0_.y;                      \
            pb[D][q_][2] = t0_.z; pb[D][q_][3] = t0_.w;                      \
            py[D][q_][0] = t1_.x; py[D][q_][1] = t1_.y;                      \
            py[D][q_][2] = t1_.z; py[D][q_][3] = t1_.w;                      \
        }                                                                    \
    } while (0)
                LOADB(0, 0);
#pragma unroll
                for (int h = 0; h < 2; ++h) {
                    const int cur = h & 1;
                    if (h < 1) LOADB(1, 1);
#pragma unroll
                    for (int q = 0; q < 4; ++q) {
#pragma unroll
                        for (int jr = 0; jr < 4; ++jr) {
                            const int j = 3 - jr;
                            const int t = ttop - (16 * h + 4 * q + jr);
                            const float lpb = pb[cur][q][j];
                            const float lpy = py[cur][q][j];
                            dp_step<FRZV>(bA, bB, b0, lpb, lpy, skipb, lgrp, l,
                                          (t >= 512) & (t <= xl - 2));
                            if (FRZV) {  // seed beta_{xl-1} in-stream
                                const bool ss = (t == xl - 1);
                                bA = ss ? ((l == ls) ? lpb : NEGV) : bA;
                                bB = ss ? ((l == ls) ? lpy : NEGV) : bB;
                                b0 = ss ? NEGV : b0;
                            }
                        }
                    }
                }
#undef LOADB
            };
            if (c == 0 || xl < kT) body(TrueT{});
            else body(FalseT{});
            __syncthreads();
        }
        // gamma_511[s] = lse(beta[s], beta[s+1], allow? beta[s+2]) = one more
        // mirror step with lp = 0 (unconditional).
        dp_step<false>(bA, bB, b0, 0.0f, 0.0f, skipb, lgrp, l, true);
        st_b[128 - 2 * l] = bA;
        st_b[127 - 2 * l] = bB;
        if (l == 0) st_b[0] = b0;
        __syncthreads();
    } else {
        // ---------------- STAGERS ----------------
        const bool isF = wid < 5;
        for (int c = 0; c < kNCH; ++c) {
            if (c + 1 < kNCH)
                stage_sm(c + 1, isF, isF ? sbf[(c + 1) & 1] : sbb[(c + 1) & 1]);
            __syncthreads();
        }
        __syncthreads();  // match the post-loop barrier
    }
}

__global__ __launch_bounds__(128) void k_reduce(const float* __restrict__ nll,
                                                float* __restrict__ out) {
    const int tid = threadIdx.x;
    float v = nll[tid];
#pragma unroll
    for (int o = 32; o > 0; o >>= 1) v += __shfl_xor(v, o);
    __shared__ float partial[2];
    if ((tid & 63) == 0) partial[tid >> 6] = v;
    __syncthreads();
    if (tid == 0) out[0] = (partial[0] + partial[1]) * (1.0f / (float)kN);
}

extern "C" void kernel_launch(void* const* d_in, const int* in_sizes, int n_in,
                              void* d_out, int out_size, void* d_ws, size_t ws_size,
                              hipStream_t stream) {
    const float* logits = (const float*)d_in[0];
    const int* y = (const int*)d_in[1];
    const int* xlens = (const int*)d_in[2];
    const int* ylens = (const int*)d_in[3];
    float* out = (float*)d_out;

    float* nll = (float*)d_ws;  // 128 floats
    k_ctc_fused<<<kN, 512, 0, stream>>>(logits, y, xlens, ylens, nll);
    k_reduce<<<1, kN, 0, stream>>>(nll, out);
}